// Round 7
// baseline (658.741 us; speedup 1.0000x reference)
//
#include <hip/hip_runtime.h>
#include <hip/hip_bf16.h>

// Problem dims (fixed by reference setup_inputs)
#define BB 2
#define TT 2048
#define DD 512
#define FF 2048
#define HH 8
#define DH 64
#define LL 2
#define MM (BB*TT)   // 4096 rows

typedef __attribute__((ext_vector_type(8))) short bf16x8;
typedef __attribute__((ext_vector_type(4))) float f32x4;

__device__ __forceinline__ float bf2f(unsigned short u) {
    return __uint_as_float(((unsigned int)u) << 16);
}
__device__ __forceinline__ unsigned short f2bf(float f) {
    unsigned int u = __float_as_uint(f);
    u += 0x7fffu + ((u >> 16) & 1u);   // round-to-nearest-even
    return (unsigned short)(u >> 16);
}
// v_cvt_pk_bf16_f32: low = a, high = b (RNE)
__device__ __forceinline__ unsigned int cvtpk(float a, float b) {
    unsigned int r;
    asm("v_cvt_pk_bf16_f32 %0, %1, %2" : "=v"(r) : "v"(a), "v"(b));
    return r;
}
__device__ __forceinline__ void gload16(const void* g, void* l) {
    __builtin_amdgcn_global_load_lds((__attribute__((address_space(1))) void*)g,
                                     (__attribute__((address_space(3))) void*)l, 16, 0, 0);
}

// ---------------------------------------------------------------------------
// LayerNorm: one block (256 threads) per row of 512 floats. bf16 or f32 out.
// ---------------------------------------------------------------------------
template<bool BF16OUT>
__global__ __launch_bounds__(256) void ln_kernel(const float* __restrict__ x,
                                                 const float* __restrict__ g,
                                                 const float* __restrict__ b,
                                                 void* __restrict__ out)
{
    const int row = blockIdx.x;
    const int tid = threadIdx.x;
    const float2 v = ((const float2*)(x + (size_t)row * DD))[tid];
    float s = v.x + v.y;
    float q = v.x * v.x + v.y * v.y;
    #pragma unroll
    for (int off = 32; off; off >>= 1) {
        s += __shfl_down(s, off);
        q += __shfl_down(q, off);
    }
    __shared__ float ss[4], qq[4];
    const int wid = tid >> 6;
    if ((tid & 63) == 0) { ss[wid] = s; qq[wid] = q; }
    __syncthreads();
    s = ss[0] + ss[1] + ss[2] + ss[3];
    q = qq[0] + qq[1] + qq[2] + qq[3];
    const float mean = s * (1.0f / DD);
    const float var = q * (1.0f / DD) - mean * mean;
    const float inv = rsqrtf(var + 1e-6f);
    const float2 gg = ((const float2*)g)[tid];
    const float2 bb = ((const float2*)b)[tid];
    const float ox = gg.x * (v.x - mean) * inv + bb.x;
    const float oy = gg.y * (v.y - mean) * inv + bb.y;
    if (BF16OUT) {
        const unsigned int pk = cvtpk(ox, oy);
        ((unsigned int*)((unsigned short*)out + (size_t)row * DD))[tid] = pk;
    } else {
        float2 o; o.x = ox; o.y = oy;
        ((float2*)((float*)out + (size_t)row * DD))[tid] = o;
    }
}

// ---------------------------------------------------------------------------
// fp32 -> bf16 elementwise (enc inputs), 2 jobs batched via z.
// ---------------------------------------------------------------------------
struct CvtEJob { const float* s; unsigned short* d; };
struct CvtEJobs2 { CvtEJob j[2]; };

__global__ __launch_bounds__(256) void cvt_kernel(CvtEJobs2 P, int n)
{
    const CvtEJob jb = P.j[blockIdx.z];
    const int i = (blockIdx.x * 256 + threadIdx.x) * 8;
    if (i >= n) return;
    const float4 a = *(const float4*)(jb.s + i);
    const float4 b = *(const float4*)(jb.s + i + 4);
    unsigned int o[4];
    o[0] = cvtpk(a.x, a.y); o[1] = cvtpk(a.z, a.w);
    o[2] = cvtpk(b.x, b.y); o[3] = cvtpk(b.z, b.w);
    *(bf16x8*)(jb.d + i) = *(bf16x8*)o;
}

// ---------------------------------------------------------------------------
// Weight convert + transpose: src fp32 [K][N] -> dst bf16 [N][K]. 32x32 tiles.
// Per-job dims; oversize grid blocks exit on bounds check.
// ---------------------------------------------------------------------------
struct CvtTJob { const float* s; unsigned short* d; int K; int N; };
struct CvtTJobs20 { CvtTJob j[20]; };

__global__ __launch_bounds__(256) void cvtT_kernel(CvtTJobs20 P)
{
    __shared__ float t[32][33];
    const CvtTJob jb = P.j[blockIdx.z];
    const int gk = blockIdx.y << 5, gn = blockIdx.x << 5;
    if (gk >= jb.K || gn >= jb.N) return;
    const int tx = threadIdx.x & 31, ty = threadIdx.x >> 5;
    #pragma unroll
    for (int i = 0; i < 4; ++i)
        t[ty + i * 8][tx] = jb.s[(size_t)(gk + ty + i * 8) * jb.N + gn + tx];
    __syncthreads();
    #pragma unroll
    for (int i = 0; i < 4; ++i)
        jb.d[(size_t)(gn + ty + i * 8) * jb.K + gk + tx] = f2bf(t[tx][ty + i * 8]);
}

// ---------------------------------------------------------------------------
// bf16 MFMA GEMM: C[M,N] = scale * A[M,K] @ Wt[N,K]^T (+res fp32) (ReLU opt).
// 128x128 tile, BK=64, 256 threads = 4 waves (2x2 of 64x64).
// Ct (optional): ALSO/INSTEAD write transposed per-head V layout
//   vt[(b*8+h)*64 + (n&63)][t = m&2047]  (b=m>>11, h=n>>6).
// ---------------------------------------------------------------------------
struct GemmJob {
    const unsigned short* A;
    const unsigned short* Wt;
    const float* res;
    float* Cf;
    unsigned short* Cb;
    unsigned short* Ct;
    float scale;
    int relu;
};
struct GemmJobs6 { GemmJob j[6]; };

__global__ __launch_bounds__(256, 2) void gemm_mfma(GemmJobs6 P, int M, int N, int K)
{
    __shared__ __align__(16) unsigned char lds[32768];   // A: 0..16K, B: 16K..32K
    const GemmJob jb = P.j[blockIdx.z];
    const int tid = threadIdx.x, lane = tid & 63, w = tid >> 6;
    const int bn = blockIdx.x << 7, bm = blockIdx.y << 7;
    const int wr = (w >> 1) << 6, wc = (w & 1) << 6;
    const size_t strA = (size_t)K * 2;

    f32x4 acc[4][4] = {};
    const int akey = (lane & 7) << 4;
    const int frow = lane & 15;
    const int kq = (lane >> 4) << 4;

    for (int kt = 0; kt < K; kt += 64) {
        __syncthreads();
        #pragma unroll
        for (int c = 0; c < 4; ++c) {
            const int q = c * 4 + w;
            const int o = (q << 10) + (lane << 4);
            const int row = o >> 7;
            const int colb = (o & 127) ^ ((row & 7) << 4);
            gload16((const char*)jb.A + (size_t)(bm + row) * strA + kt * 2 + colb,
                    lds + (q << 10));
            gload16((const char*)jb.Wt + (size_t)(bn + row) * strA + kt * 2 + colb,
                    lds + 16384 + (q << 10));
        }
        asm volatile("s_waitcnt vmcnt(0)" ::: "memory");
        __syncthreads();
        #pragma unroll
        for (int kk = 0; kk < 2; ++kk) {
            bf16x8 av[4], bv[4];
            #pragma unroll
            for (int i = 0; i < 4; ++i) {
                const int rA = wr + (i << 4) + frow;
                av[i] = *(const bf16x8*)(lds + (rA << 7) + ((((kk << 6) + kq)) ^ akey));
                const int rB = wc + (i << 4) + frow;
                bv[i] = *(const bf16x8*)(lds + 16384 + (rB << 7) + ((((kk << 6) + kq)) ^ akey));
            }
            #pragma unroll
            for (int i = 0; i < 4; ++i)
                #pragma unroll
                for (int j = 0; j < 4; ++j)
                    acc[i][j] = __builtin_amdgcn_mfma_f32_16x16x32_bf16(av[i], bv[j], acc[i][j], 0, 0, 0);
        }
    }

    const int crow0 = (lane >> 4) << 2;
    const int ccol = lane & 15;
    if (jb.Ct) {
        // transposed per-head V write (4 consecutive t per uint2)
        #pragma unroll
        for (int i = 0; i < 4; ++i)
            #pragma unroll
            for (int j = 0; j < 4; ++j) {
                const int gm = bm + wr + (i << 4) + crow0;   // 4-aligned
                const int gn = bn + wc + (j << 4) + ccol;
                const int bI = gm >> 11, t = gm & 2047;
                const int hI = gn >> 6, d = gn & 63;
                uint2 pk;
                pk.x = cvtpk(acc[i][j][0], acc[i][j][1]);
                pk.y = cvtpk(acc[i][j][2], acc[i][j][3]);
                *(uint2*)(jb.Ct + ((size_t)((bI * HH + hI) * DH + d)) * TT + t) = pk;
            }
        return;
    }
    #pragma unroll
    for (int i = 0; i < 4; ++i) {
        #pragma unroll
        for (int j = 0; j < 4; ++j) {
            #pragma unroll
            for (int r = 0; r < 4; ++r) {
                const int gm = bm + wr + (i << 4) + crow0 + r;
                const int gn = bn + wc + (j << 4) + ccol;
                float v = acc[i][j][r] * jb.scale;
                if (jb.relu) v = fmaxf(v, 0.f);
                const size_t idx = (size_t)gm * N + gn;
                if (jb.res) v += jb.res[idx];
                if (jb.Cf) jb.Cf[idx] = v;
                if (jb.Cb) jb.Cb[idx] = f2bf(v);
            }
        }
    }
}

// ---------------------------------------------------------------------------
// MFMA flash attention v4: block double-buffered K/V^T staging + defer-max
// (log2-domain: logits pre-scaled by log2e via qscale; exp2f everywhere).
// NQ q-blocks (16 rows each) per wave: K/V fragment reads amortize over NQ.
// ---------------------------------------------------------------------------
template<bool CAUSAL, bool DUAL, bool STOREML, int NQ>
__global__ __launch_bounds__(256, 2) void flash_mfma(
    const unsigned short* __restrict__ q,
    const unsigned short* __restrict__ ka, const unsigned short* __restrict__ vta,
    const unsigned short* __restrict__ kc, const unsigned short* __restrict__ vtc,
    unsigned short* __restrict__ outa, unsigned short* __restrict__ outc,
    float* __restrict__ ml)
{
    // LDS: Kbuf[2] @ 0/8192, Vbuf[2] @ 16384/24576, P @ 32768 + w*NQ*2048
    __shared__ __align__(16) char lds[49152];
    const int tid = threadIdx.x;
    const int lane = tid & 63, w = tid >> 6;
    const int g4 = lane >> 4, c = lane & 15;

    constexpr int GX = 32 / NQ;
    const int f = blockIdx.x + GX * (blockIdx.y + 8 * blockIdx.z);
    const int xcd = f & 7;
    const int tt = f >> 3;
    const int jq = tt % GX;
    const int grp = (tt / GX) * 8 + xcd;
    int b, h, which;
    if (DUAL) { which = grp & 1; b = (grp >> 1) & 1; h = grp >> 2; }
    else      { which = 0;       b = grp & 1;        h = grp >> 1; }
    const int q0 = jq * (64 * NQ);
    const int q0w = q0 + w * (16 * NQ);
    const int kendw = q0w + 16 * NQ;

    const unsigned short* k  = (DUAL && which) ? kc : ka;
    const unsigned short* vt = (DUAL && which) ? vtc : vta;
    unsigned short* out = (DUAL && which) ? outc : outa;

    bf16x8 Qf[NQ][2];
    #pragma unroll
    for (int jb = 0; jb < NQ; ++jb) {
        const unsigned short* qp = q + (size_t)(b * TT + q0w + (jb << 4) + c) * DD + h * DH + (g4 << 3);
        Qf[jb][0] = *(const bf16x8*)qp;
        Qf[jb][1] = *(const bf16x8*)(qp + 32);
    }
    const char* kbase = (const char*)(k + (size_t)b * TT * DD + h * DH);
    const char* vtb   = (const char*)(vt + (size_t)(b * HH + h) * DH * TT);
    char* Pw = lds + 32768 + w * (NQ * 2048);
    const int pkey = (c & 7) << 4;

    f32x4 O[NQ][4] = {};
    float mval[NQ], lpart[NQ];
    #pragma unroll
    for (int jb = 0; jb < NQ; ++jb) { mval[jb] = -1e30f; lpart[jb] = 0.f; }

    const int nt = CAUSAL ? ((q0 + 64 * NQ) >> 6) : (TT >> 6);

    auto STAGE = [&](int t, int sel) {
        const int kt = t << 6;
        char* Kb = lds + sel * 8192;
        char* Vb = lds + 16384 + sel * 8192;
        #pragma unroll
        for (int c8 = 0; c8 < 2; ++c8) {
            const int qc = (c8 << 2) + w;            // chunk 0..7 (1KB each)
            const int o = (qc << 10) + (lane << 4);
            const int row = o >> 7;                  // 0..63
            const int colb = (o & 127) ^ ((row & 7) << 4);
            gload16(kbase + (size_t)(kt + row) * (DD * 2) + colb, Kb + (qc << 10));
            gload16(vtb + (size_t)row * (TT * 2) + kt * 2 + colb, Vb + (qc << 10));
        }
    };

    STAGE(0, 0);
    asm volatile("s_waitcnt vmcnt(0)" ::: "memory");
    __syncthreads();

    for (int t = 0; t < nt; ++t) {
        const int cur = t & 1;
        if (t + 1 < nt) STAGE(t + 1, cur ^ 1);
        const int kt = t << 6;

        if (!CAUSAL || kt < kendw) {   // skip fully-masked tiles (barriers kept)
            const char* Kb = lds + cur * 8192;
            const char* Vb = lds + 16384 + cur * 8192;

            // ---- QK^T (swapped): s[jb][i] = S^T[k][q], K-frags shared over jb
            f32x4 s[NQ][4] = {};
            #pragma unroll
            for (int kk = 0; kk < 2; ++kk) {
                bf16x8 av[4];
                #pragma unroll
                for (int i = 0; i < 4; ++i) {
                    const int r = (i << 4) + c;
                    av[i] = *(const bf16x8*)(Kb + (r << 7) + (((kk << 6) + (g4 << 4)) ^ ((r & 7) << 4)));
                }
                #pragma unroll
                for (int i = 0; i < 4; ++i)
                    #pragma unroll
                    for (int jb = 0; jb < NQ; ++jb)
                        s[jb][i] = __builtin_amdgcn_mfma_f32_16x16x32_bf16(av[i], Qf[jb][kk], s[jb][i], 0, 0, 0);
            }

            #pragma unroll
            for (int jb = 0; jb < NQ; ++jb) {
                const int qbase = q0w + (jb << 4);
                if (CAUSAL && kt + 63 > qbase) {   // diagonal: elementwise mask
                    #pragma unroll
                    for (int i = 0; i < 4; ++i)
                        #pragma unroll
                        for (int r = 0; r < 4; ++r)
                            if (kt + (i << 4) + (g4 << 2) + r > qbase + c) s[jb][i][r] = -1e30f;
                }
                // defer-max online softmax (log2 domain, thr 11 ~ e^8)
                float pmax = -1e30f;
                #pragma unroll
                for (int i = 0; i < 4; ++i)
                    #pragma unroll
                    for (int r = 0; r < 4; ++r) pmax = fmaxf(pmax, s[jb][i][r]);
                if (__any(pmax > mval[jb] + 11.f)) {
                    float mx = fmaxf(pmax, __shfl_xor(pmax, 16));
                    mx = fmaxf(mx, __shfl_xor(mx, 32));
                    const float mn = fmaxf(mval[jb], mx);
                    const float scf = exp2f(mval[jb] - mn);
                    lpart[jb] *= scf;
                    #pragma unroll
                    for (int r = 0; r < 4; ++r) {
                        const float fr = __shfl(scf, (g4 << 2) + r);
                        #pragma unroll
                        for (int jj = 0; jj < 4; ++jj) O[jb][jj][r] *= fr;
                    }
                    mval[jb] = mn;
                }
                float ps = 0.f;
                #pragma unroll
                for (int i = 0; i < 4; ++i)
                    #pragma unroll
                    for (int r = 0; r < 4; ++r) {
                        const float p = exp2f(s[jb][i][r] - mval[jb]);
                        s[jb][i][r] = p;
                        ps += p;
                    }
                lpart[jb] += ps;
                // P -> LDS (row q = jb*16+c)
                #pragma unroll
                for (int i = 0; i < 4; ++i) {
                    uint2 pk;
                    pk.x = cvtpk(s[jb][i][0], s[jb][i][1]);
                    pk.y = cvtpk(s[jb][i][2], s[jb][i][3]);
                    const int baddr = (((jb << 4) + c) << 7) + (((i << 4) + (g4 << 2)) << 1);
                    *(uint2*)(Pw + (baddr ^ pkey)) = pk;
                }
            }
            asm volatile("s_waitcnt lgkmcnt(0)" ::: "memory");
            __builtin_amdgcn_sched_barrier(0);

            // ---- PV: O[jb] += P[jb] @ Vt^T, V-frags shared over jb ----
            #pragma unroll
            for (int kk = 0; kk < 2; ++kk) {
                bf16x8 pa[NQ];
                #pragma unroll
                for (int jb = 0; jb < NQ; ++jb)
                    pa[jb] = *(const bf16x8*)(Pw + (((((jb << 4) + c) << 7) + (kk << 6) + (g4 << 4)) ^ pkey));
                #pragma unroll
                for (int jj = 0; jj < 4; ++jj) {
                    const int d = (jj << 4) + c;
                    const bf16x8 vb = *(const bf16x8*)(Vb + (d << 7) + (((kk << 6) + (g4 << 4)) ^ ((d & 7) << 4)));
                    #pragma unroll
                    for (int jb = 0; jb < NQ; ++jb)
                        O[jb][jj] = __builtin_amdgcn_mfma_f32_16x16x32_bf16(pa[jb], vb, O[jb][jj], 0, 0, 0);
                }
            }
        }

        asm volatile("s_waitcnt vmcnt(0)" ::: "memory");
        __syncthreads();
    }

    // ---- epilogue per q-block ----
    #pragma unroll
    for (int jb = 0; jb < NQ; ++jb) {
        float l2 = lpart[jb] + __shfl_xor(lpart[jb], 16);
        const float ltot = l2 + __shfl_xor(l2, 32);
        float invL[4];
        #pragma unroll
        for (int r = 0; r < 4; ++r) invL[r] = 1.f / __shfl(ltot, (g4 << 2) + r);
        #pragma unroll
        for (int jj = 0; jj < 4; ++jj)
            #pragma unroll
            for (int r = 0; r < 4; ++r) {
                const int qr = q0w + (jb << 4) + (g4 << 2) + r;
                out[(size_t)(b * TT + qr) * DD + h * DH + (jj << 4) + c] = f2bf(O[jb][jj][r] * invL[r]);
            }
        if (STOREML && (!DUAL || which == 1) && lane < 16) {
            const size_t mi = (((size_t)b * HH + h) * TT + q0w + (jb << 4) + lane) * 2;
            ml[mi] = mval[jb];      // log2-domain m
            ml[mi + 1] = ltot;
        }
    }
}

// ---------------------------------------------------------------------------
// bf16 elementwise add (attn_a + attn_c -> attn_sum).
// ---------------------------------------------------------------------------
__global__ __launch_bounds__(256) void sum_bf16_kernel(const unsigned short* __restrict__ a,
                                                       const unsigned short* __restrict__ b,
                                                       unsigned short* __restrict__ o, int n)
{
    const int i = (blockIdx.x * 256 + threadIdx.x) * 8;
    if (i >= n) return;
    const bf16x8 av = *(const bf16x8*)(a + i);
    const bf16x8 bv = *(const bf16x8*)(b + i);
    unsigned int ov[4];
    #pragma unroll
    for (int e = 0; e < 4; ++e) {
        const float lo = bf2f(((const unsigned short*)&av)[2 * e]) + bf2f(((const unsigned short*)&bv)[2 * e]);
        const float hi = bf2f(((const unsigned short*)&av)[2 * e + 1]) + bf2f(((const unsigned short*)&bv)[2 * e + 1]);
        ov[e] = cvtpk(lo, hi);
    }
    *(bf16x8*)(o + i) = *(bf16x8*)ov;
}

// ---------------------------------------------------------------------------
// avg via MFMA: avg[b,q,kt] (+)= (1/(H*L)) * sum_h exp2(q.kc - m)/l
// (q pre-scaled by dh^-0.5 * log2e; m stored in log2 domain by flash)
// ---------------------------------------------------------------------------
__global__ __launch_bounds__(64) void avg_mfma_kernel(const unsigned short* __restrict__ qm,
                                                      const unsigned short* __restrict__ kcm,
                                                      const float* __restrict__ ml,
                                                      float* __restrict__ avg, int first)
{
    __shared__ __align__(16) unsigned char ldsQ[8192];
    __shared__ __align__(16) unsigned char ldsK[8192];
    __shared__ float sM[8][64];
    __shared__ float sIL[8][64];
    const int lane = threadIdx.x;
    const int kt0 = blockIdx.x << 6, q0 = blockIdx.y << 6, b = blockIdx.z;

    #pragma unroll
    for (int h = 0; h < 8; ++h) {
        const float* mp = ml + (((size_t)(b * HH + h) * TT) + q0 + lane) * 2;
        sM[h][lane] = mp[0];
        sIL[h][lane] = 1.f / mp[1];
    }

    float avac[4][4][4] = {};
    const int akey = (lane & 7) << 4;
    const int frow = lane & 15;
    const int kq = (lane >> 4) << 4;
    const int crow0 = (lane >> 4) << 2;

    for (int h = 0; h < 8; ++h) {
        __syncthreads();
        #pragma unroll
        for (int c = 0; c < 8; ++c) {
            const int o = (c << 10) + (lane << 4);
            const int row = o >> 7;
            const int colb = (o & 127) ^ ((row & 7) << 4);
            gload16((const char*)qm + ((size_t)(b * TT + q0 + row) * DD + h * DH) * 2 + colb,
                    ldsQ + (c << 10));
            gload16((const char*)kcm + ((size_t)(b * TT + kt0 + row) * DD + h * DH) * 2 + colb,
                    ldsK + (c << 10));
        }
        asm volatile("s_waitcnt vmcnt(0)" ::: "memory");
        __syncthreads();
        f32x4 s[4][4] = {};
        #pragma unroll
        for (int kk = 0; kk < 2; ++kk) {
            bf16x8 qv[4], kv[4];
            #pragma unroll
            for (int i = 0; i < 4; ++i) {
                qv[i] = *(const bf16x8*)(ldsQ + (((i << 4) + frow) << 7) + (((kk << 6) + kq) ^ akey));
                kv[i] = *(const bf16x8*)(ldsK + (((i << 4) + frow) << 7) + (((kk << 6) + kq) ^ akey));
            }
            #pragma unroll
            for (int i = 0; i < 4; ++i)
                #pragma unroll
                for (int j = 0; j < 4; ++j)
                    s[i][j] = __builtin_amdgcn_mfma_f32_16x16x32_bf16(qv[i], kv[j], s[i][j], 0, 0, 0);
        }
        #pragma unroll
        for (int i = 0; i < 4; ++i)
            #pragma unroll
            for (int j = 0; j < 4; ++j)
                #pragma unroll
                for (int r = 0; r < 4; ++r) {
                    const int qr = (i << 4) + crow0 + r;
                    avac[i][j][r] += exp2f(s[i][j][r] - sM[h][qr]) * sIL[h][qr];
                }
    }

    float* dst = avg + ((size_t)b * TT + q0) * TT + kt0;
    #pragma unroll
    for (int i = 0; i < 4; ++i)
        #pragma unroll
        for (int j = 0; j < 4; ++j)
            #pragma unroll
            for (int r = 0; r < 4; ++r) {
                const int qr = (i << 4) + crow0 + r;
                const int kc = (j << 4) + (lane & 15);
                const float v = avac[i][j][r] * (1.f / (HH * LL));
                float* p = dst + (size_t)qr * TT + kc;
                *p = first ? v : (*p + v);
            }
}

// ---------------------------------------------------------------------------
extern "C" void kernel_launch(void* const* d_in, const int* in_sizes, int n_in,
                              void* d_out, int out_size, void* d_ws, size_t ws_size,
                              hipStream_t stream)
{
    const float* x_in   = (const float*)d_in[0];
    const float* enc_a  = (const float*)d_in[1];
    const float* enc_c  = (const float*)d_in[2];
    const float* sa_wq0 = (const float*)d_in[3];
    const float* sa_wk0 = (const float*)d_in[4];
    const float* sa_wv0 = (const float*)d_in[5];
    const float* sa_wo0 = (const float*)d_in[6];
    const float* ed_wq0 = (const float*)d_in[7];
    const float* ed_wk0 = (const float*)d_in[8];
    const float* ed_wv0 = (const float*)d_in[9];
    const float* ed_wo0 = (const float*)d_in[10];
    const float* ffn_w10 = (const float*)d_in[11];
    const float* ffn_w20 = (const float*)d_in[12];
    const float* ln1_g0 = (const float*)d_in[13];
    const float* ln1_b0 = (const float*)d_in[14];
    const float* ln2_g0 = (const float*)d_in[15];
    const float* ln2_b0 = (const float*)d_in[16];
    const float* ln3_g0 = (const float*)d_in[17];
    const float* ln3_b0 = (const float*)d_in[18];
    const float* out_g  = (const float*)d_in[19];
    const float* out_b  = (const float*)d_in[20];

    const size_t NTD = (size_t)MM * DD;       // 2,097,152
    const size_t MB = 1u << 20;
    char* W = (char*)d_ws;
    float*          x_buf   = (float*)(W);                   // 8 MB
    unsigned short* h_bf    = (unsigned short*)(W + 8 * MB); // 4 MB
    unsigned short* q_bf    = (unsigned short*)(W + 12 * MB);
    unsigned short* k1_bf   = (unsigned short*)(W + 16 * MB);
    unsigned short* vt1     = (unsigned short*)(W + 20 * MB); // V_a^T per-head
    unsigned short* k2_bf   = (unsigned short*)(W + 24 * MB);
    unsigned short* vt2     = (unsigned short*)(W + 28 * MB); // V_c^T per-head
    unsigned short* attnA   = (unsigned short*)(W + 32 * MB);
    unsigned short* attnC   = (unsigned short*)(W + 36 * MB);
    float*          ml_buf  = (float*)(W + 40 * MB);         // 256 KB
    unsigned short* encA_bf = (unsigned short*)(W + 41 * MB);
    unsigned short* encC_bf = (unsigned short*)(W + 45 * MB);
    unsigned short* wbf     = (unsigned short*)(W + 49 * MB); // 16.8 MB
    unsigned short* ffn_bf  = q_bf;   // alias (spans q..k2, all dead in FFN)
    unsigned short* attnS   = h_bf;   // alias (h dead after projections)

    unsigned short* w1t = wbf + (size_t)16 * DD * DD;
    unsigned short* w2t = w1t + (size_t)2 * DD * FF;
    auto wd = [&](int l, int which) { return wbf + ((size_t)(l * 8 + which)) * DD * DD; };

    float* x_out   = (float*)d_out;
    float* avg_out = (float*)d_out + NTD;

    hipMemcpyAsync(x_buf, x_in, NTD * sizeof(float), hipMemcpyDeviceToDevice, stream);

    // ---- setup: all weight transposes in ONE dispatch, enc converts in one ----
    {
        CvtTJobs20 J{};
        const float* srcs[8] = {sa_wq0, sa_wk0, sa_wv0, sa_wo0, ed_wq0, ed_wk0, ed_wv0, ed_wo0};
        for (int l = 0; l < LL; ++l)
            for (int t = 0; t < 8; ++t)
                J.j[l * 8 + t] = {srcs[t] + (size_t)l * DD * DD, wd(l, t), DD, DD};
        for (int l = 0; l < LL; ++l) {
            J.j[16 + l] = {ffn_w10 + (size_t)l * DD * FF, w1t + (size_t)l * FF * DD, DD, FF};
            J.j[18 + l] = {ffn_w20 + (size_t)l * FF * DD, w2t + (size_t)l * DD * FF, FF, DD};
        }
        cvtT_kernel<<<dim3(FF / 32, FF / 32, 20), 256, 0, stream>>>(J);
    }
    {
        CvtEJobs2 J{};
        J.j[0] = {enc_a, encA_bf};
        J.j[1] = {enc_c, encC_bf};
        cvt_kernel<<<dim3(NTD / 8 / 256, 1, 2), 256, 0, stream>>>(J, (int)NTD);
    }

    const dim3 flashSelfG(32, HH, BB);       // NQ=1: (32, 8, 2)
    const dim3 flashCrossG(16, HH, BB * 2);  // NQ=2: (16, 8, 4)
    const dim3 avgG(TT / 64, TT / 64, BB);
    const float qscale = 0.125f * 1.4426950408889634f;  // dh^-0.5 * log2(e)

    for (int i = 0; i < LL; ++i) {
        const size_t fOff = (size_t)i * DD * FF;
        const size_t lOff = (size_t)i * DD;

        // --- self attention ---
        ln_kernel<true><<<MM, 256, 0, stream>>>(x_buf, ln1_g0 + lOff, ln1_b0 + lOff, h_bf);
        {
            GemmJobs6 J{};
            J.j[0] = {h_bf, wd(i, 0), nullptr, nullptr, q_bf, nullptr, qscale, 0};
            J.j[1] = {h_bf, wd(i, 1), nullptr, nullptr, k1_bf, nullptr, 1.f, 0};
            J.j[2] = {h_bf, wd(i, 2), nullptr, nullptr, nullptr, vt1, 1.f, 0};
            gemm_mfma<<<dim3(DD / 128, MM / 128, 3), 256, 0, stream>>>(J, MM, DD, DD);
        }
        flash_mfma<true, false, false, 1><<<flashSelfG, 256, 0, stream>>>(
            q_bf, k1_bf, vt1, nullptr, nullptr, attnA, nullptr, nullptr);
        {
            GemmJobs6 J{};
            J.j[0] = {attnA, wd(i, 3), x_buf, x_buf, nullptr, nullptr, 1.f, 0};
            gemm_mfma<<<dim3(DD / 128, MM / 128, 1), 256, 0, stream>>>(J, MM, DD, DD);
        }

        // --- cross attention (enc_a + enc_c, shared weights) ---
        ln_kernel<true><<<MM, 256, 0, stream>>>(x_buf, ln2_g0 + lOff, ln2_b0 + lOff, h_bf);
        {
            GemmJobs6 J{};
            J.j[0] = {h_bf,    wd(i, 4), nullptr, nullptr, q_bf, nullptr, qscale, 0};
            J.j[1] = {encA_bf, wd(i, 5), nullptr, nullptr, k1_bf, nullptr, 1.f, 0};
            J.j[2] = {encA_bf, wd(i, 6), nullptr, nullptr, nullptr, vt1, 1.f, 0};
            J.j[3] = {encC_bf, wd(i, 5), nullptr, nullptr, k2_bf, nullptr, 1.f, 0};
            J.j[4] = {encC_bf, wd(i, 6), nullptr, nullptr, nullptr, vt2, 1.f, 0};
            gemm_mfma<<<dim3(DD / 128, MM / 128, 5), 256, 0, stream>>>(J, MM, DD, DD);
        }
        flash_mfma<false, true, true, 2><<<flashCrossG, 256, 0, stream>>>(
            q_bf, k1_bf, vt1, k2_bf, vt2, attnA, attnC, ml_buf);
        sum_bf16_kernel<<<NTD / 8 / 256, 256, 0, stream>>>(attnA, attnC, attnS, (int)NTD);
        avg_mfma_kernel<<<avgG, 64, 0, stream>>>(q_bf, k2_bf, ml_buf, avg_out, (i == 0) ? 1 : 0);
        {
            GemmJobs6 J{};
            J.j[0] = {attnS, wd(i, 7), x_buf, x_buf, nullptr, nullptr, 1.f, 0};
            gemm_mfma<<<dim3(DD / 128, MM / 128, 1), 256, 0, stream>>>(J, MM, DD, DD);
        }

        // --- FFN ---
        ln_kernel<true><<<MM, 256, 0, stream>>>(x_buf, ln3_g0 + lOff, ln3_b0 + lOff, h_bf);
        {
            GemmJobs6 J{};
            J.j[0] = {h_bf, w1t + fOff, nullptr, nullptr, ffn_bf, nullptr, 1.f, 1};
            gemm_mfma<<<dim3(FF / 128, MM / 128, 1), 256, 0, stream>>>(J, MM, FF, DD);
        }
        {
            GemmJobs6 J{};
            J.j[0] = {ffn_bf, w2t + fOff, x_buf, x_buf, nullptr, nullptr, 1.f, 0};
            gemm_mfma<<<dim3(DD / 128, MM / 128, 1), 256, 0, stream>>>(J, MM, DD, FF);
        }
    }

    ln_kernel<false><<<MM, 256, 0, stream>>>(x_buf, out_g, out_b, x_out);
}

// Round 8
// 644.785 us; speedup vs baseline: 1.0216x; 1.0216x over previous
//
#include <hip/hip_runtime.h>
#include <hip/hip_bf16.h>

// Problem dims (fixed by reference setup_inputs)
#define BB 2
#define TT 2048
#define DD 512
#define FF 2048
#define HH 8
#define DH 64
#define LL 2
#define MM (BB*TT)   // 4096 rows

typedef __attribute__((ext_vector_type(8))) short bf16x8;
typedef __attribute__((ext_vector_type(4))) float f32x4;

__device__ __forceinline__ float bf2f(unsigned short u) {
    return __uint_as_float(((unsigned int)u) << 16);
}
__device__ __forceinline__ unsigned short f2bf(float f) {
    unsigned int u = __float_as_uint(f);
    u += 0x7fffu + ((u >> 16) & 1u);   // round-to-nearest-even
    return (unsigned short)(u >> 16);
}
// v_cvt_pk_bf16_f32: low = a, high = b (RNE)
__device__ __forceinline__ unsigned int cvtpk(float a, float b) {
    unsigned int r;
    asm("v_cvt_pk_bf16_f32 %0, %1, %2" : "=v"(r) : "v"(a), "v"(b));
    return r;
}
__device__ __forceinline__ void gload16(const void* g, void* l) {
    __builtin_amdgcn_global_load_lds((__attribute__((address_space(1))) void*)g,
                                     (__attribute__((address_space(3))) void*)l, 16, 0, 0);
}

// ---------------------------------------------------------------------------
// LayerNorm: one block (256 threads) per row of 512 floats. bf16 or f32 out.
// ---------------------------------------------------------------------------
template<bool BF16OUT>
__global__ __launch_bounds__(256) void ln_kernel(const float* __restrict__ x,
                                                 const float* __restrict__ g,
                                                 const float* __restrict__ b,
                                                 void* __restrict__ out)
{
    const int row = blockIdx.x;
    const int tid = threadIdx.x;
    const float2 v = ((const float2*)(x + (size_t)row * DD))[tid];
    float s = v.x + v.y;
    float q = v.x * v.x + v.y * v.y;
    #pragma unroll
    for (int off = 32; off; off >>= 1) {
        s += __shfl_down(s, off);
        q += __shfl_down(q, off);
    }
    __shared__ float ss[4], qq[4];
    const int wid = tid >> 6;
    if ((tid & 63) == 0) { ss[wid] = s; qq[wid] = q; }
    __syncthreads();
    s = ss[0] + ss[1] + ss[2] + ss[3];
    q = qq[0] + qq[1] + qq[2] + qq[3];
    const float mean = s * (1.0f / DD);
    const float var = q * (1.0f / DD) - mean * mean;
    const float inv = rsqrtf(var + 1e-6f);
    const float2 gg = ((const float2*)g)[tid];
    const float2 bb = ((const float2*)b)[tid];
    const float ox = gg.x * (v.x - mean) * inv + bb.x;
    const float oy = gg.y * (v.y - mean) * inv + bb.y;
    if (BF16OUT) {
        const unsigned int pk = cvtpk(ox, oy);
        ((unsigned int*)((unsigned short*)out + (size_t)row * DD))[tid] = pk;
    } else {
        float2 o; o.x = ox; o.y = oy;
        ((float2*)((float*)out + (size_t)row * DD))[tid] = o;
    }
}

// ---------------------------------------------------------------------------
// fp32 -> bf16 elementwise (enc inputs), 2 jobs batched via z.
// ---------------------------------------------------------------------------
struct CvtEJob { const float* s; unsigned short* d; };
struct CvtEJobs2 { CvtEJob j[2]; };

__global__ __launch_bounds__(256) void cvt_kernel(CvtEJobs2 P, int n)
{
    const CvtEJob jb = P.j[blockIdx.z];
    const int i = (blockIdx.x * 256 + threadIdx.x) * 8;
    if (i >= n) return;
    const float4 a = *(const float4*)(jb.s + i);
    const float4 b = *(const float4*)(jb.s + i + 4);
    unsigned int o[4];
    o[0] = cvtpk(a.x, a.y); o[1] = cvtpk(a.z, a.w);
    o[2] = cvtpk(b.x, b.y); o[3] = cvtpk(b.z, b.w);
    *(bf16x8*)(jb.d + i) = *(bf16x8*)o;
}

// ---------------------------------------------------------------------------
// Weight convert + transpose: src fp32 [K][N] -> dst bf16 [N][K]. 32x32 tiles.
// ---------------------------------------------------------------------------
struct CvtTJob { const float* s; unsigned short* d; int K; int N; };
struct CvtTJobs20 { CvtTJob j[20]; };

__global__ __launch_bounds__(256) void cvtT_kernel(CvtTJobs20 P)
{
    __shared__ float t[32][33];
    const CvtTJob jb = P.j[blockIdx.z];
    const int gk = blockIdx.y << 5, gn = blockIdx.x << 5;
    if (gk >= jb.K || gn >= jb.N) return;
    const int tx = threadIdx.x & 31, ty = threadIdx.x >> 5;
    #pragma unroll
    for (int i = 0; i < 4; ++i)
        t[ty + i * 8][tx] = jb.s[(size_t)(gk + ty + i * 8) * jb.N + gn + tx];
    __syncthreads();
    #pragma unroll
    for (int i = 0; i < 4; ++i)
        jb.d[(size_t)(gn + ty + i * 8) * jb.K + gk + tx] = f2bf(t[tx][ty + i * 8]);
}

// ---------------------------------------------------------------------------
// bf16 MFMA GEMM: C[M,N] = scale * A[M,K] @ Wt[N,K]^T (+res fp32) (ReLU opt).
// 128x128 tile, BK=64, 256 threads = 4 waves (2x2 of 64x64).
// Ct (optional): write transposed per-head V layout instead.
// ---------------------------------------------------------------------------
struct GemmJob {
    const unsigned short* A;
    const unsigned short* Wt;
    const float* res;
    float* Cf;
    unsigned short* Cb;
    unsigned short* Ct;
    float scale;
    int relu;
};
struct GemmJobs6 { GemmJob j[6]; };

__global__ __launch_bounds__(256, 2) void gemm_mfma(GemmJobs6 P, int M, int N, int K)
{
    __shared__ __align__(16) unsigned char lds[32768];   // A: 0..16K, B: 16K..32K
    const GemmJob jb = P.j[blockIdx.z];
    const int tid = threadIdx.x, lane = tid & 63, w = tid >> 6;
    const int bn = blockIdx.x << 7, bm = blockIdx.y << 7;
    const int wr = (w >> 1) << 6, wc = (w & 1) << 6;
    const size_t strA = (size_t)K * 2;

    f32x4 acc[4][4] = {};
    const int akey = (lane & 7) << 4;
    const int frow = lane & 15;
    const int kq = (lane >> 4) << 4;

    for (int kt = 0; kt < K; kt += 64) {
        __syncthreads();
        #pragma unroll
        for (int c = 0; c < 4; ++c) {
            const int q = c * 4 + w;
            const int o = (q << 10) + (lane << 4);
            const int row = o >> 7;
            const int colb = (o & 127) ^ ((row & 7) << 4);
            gload16((const char*)jb.A + (size_t)(bm + row) * strA + kt * 2 + colb,
                    lds + (q << 10));
            gload16((const char*)jb.Wt + (size_t)(bn + row) * strA + kt * 2 + colb,
                    lds + 16384 + (q << 10));
        }
        asm volatile("s_waitcnt vmcnt(0)" ::: "memory");
        __syncthreads();
        #pragma unroll
        for (int kk = 0; kk < 2; ++kk) {
            bf16x8 av[4], bv[4];
            #pragma unroll
            for (int i = 0; i < 4; ++i) {
                const int rA = wr + (i << 4) + frow;
                av[i] = *(const bf16x8*)(lds + (rA << 7) + ((((kk << 6) + kq)) ^ akey));
                const int rB = wc + (i << 4) + frow;
                bv[i] = *(const bf16x8*)(lds + 16384 + (rB << 7) + ((((kk << 6) + kq)) ^ akey));
            }
            #pragma unroll
            for (int i = 0; i < 4; ++i)
                #pragma unroll
                for (int j = 0; j < 4; ++j)
                    acc[i][j] = __builtin_amdgcn_mfma_f32_16x16x32_bf16(av[i], bv[j], acc[i][j], 0, 0, 0);
        }
    }

    const int crow0 = (lane >> 4) << 2;
    const int ccol = lane & 15;
    if (jb.Ct) {
        #pragma unroll
        for (int i = 0; i < 4; ++i)
            #pragma unroll
            for (int j = 0; j < 4; ++j) {
                const int gm = bm + wr + (i << 4) + crow0;   // 4-aligned
                const int gn = bn + wc + (j << 4) + ccol;
                const int bI = gm >> 11, t = gm & 2047;
                const int hI = gn >> 6, d = gn & 63;
                uint2 pk;
                pk.x = cvtpk(acc[i][j][0], acc[i][j][1]);
                pk.y = cvtpk(acc[i][j][2], acc[i][j][3]);
                *(uint2*)(jb.Ct + ((size_t)((bI * HH + hI) * DH + d)) * TT + t) = pk;
            }
        return;
    }
    #pragma unroll
    for (int i = 0; i < 4; ++i) {
        #pragma unroll
        for (int j = 0; j < 4; ++j) {
            #pragma unroll
            for (int r = 0; r < 4; ++r) {
                const int gm = bm + wr + (i << 4) + crow0 + r;
                const int gn = bn + wc + (j << 4) + ccol;
                float v = acc[i][j][r] * jb.scale;
                if (jb.relu) v = fmaxf(v, 0.f);
                const size_t idx = (size_t)gm * N + gn;
                if (jb.res) v += jb.res[idx];
                if (jb.Cf) jb.Cf[idx] = v;
                if (jb.Cb) jb.Cb[idx] = f2bf(v);
            }
        }
    }
}

// ---------------------------------------------------------------------------
// MFMA flash attention v5: KV-split-2 with global bf16 partials.
// Each block handles one (stream, q-tile, kv-half): double-buffered K/V^T LDS
// staging, defer-max softmax (log2 domain), NQ q-blocks (16 rows) per wave.
// Outputs UNNORMALIZED O (bf16) + per-row (m, l) f32 to partial slot
// slot = which*2 + half; merge_kernel combines.
// ---------------------------------------------------------------------------
template<bool CAUSAL, bool DUAL, int NQ>
__global__ __launch_bounds__(256, (NQ == 1) ? 4 : 3) void flash_mfma(
    const unsigned short* __restrict__ q,
    const unsigned short* __restrict__ ka, const unsigned short* __restrict__ vta,
    const unsigned short* __restrict__ kc, const unsigned short* __restrict__ vtc,
    unsigned short* __restrict__ Opart,   // [slot][MM*DD] bf16
    float* __restrict__ mlpart)           // [slot][BB*HH*TT][2] f32
{
    // LDS: Kbuf[2] @ 0/8192, Vbuf[2] @ 16384/24576, P @ 32768 + w*NQ*2048
    __shared__ __align__(16) char lds[(NQ == 1) ? 40960 : 49152];
    const int tid = threadIdx.x;
    const int lane = tid & 63, w = tid >> 6;
    const int g4 = lane >> 4, c = lane & 15;

    constexpr int GX = (32 / NQ) * 2;   // q-tiles * halves = gridDim.x
    const int f = blockIdx.x + GX * (blockIdx.y + 8 * blockIdx.z);
    const int xcd = f & 7;
    const int tt = f >> 3;
    const int u = tt % GX;
    const int half = u & 1, jq = u >> 1;
    const int grp = (tt / GX) * 8 + xcd;
    int b, h, which;
    if (DUAL) { which = grp & 1; b = (grp >> 1) & 1; h = grp >> 2; }
    else      { which = 0;       b = grp & 1;        h = grp >> 1; }
    const int q0 = jq * (64 * NQ);
    const int q0w = q0 + w * (16 * NQ);
    const int kendw = q0w + 16 * NQ;

    const unsigned short* k  = (DUAL && which) ? kc : ka;
    const unsigned short* vt = (DUAL && which) ? vtc : vta;
    const int slot = (DUAL ? (which << 1) : 0) + half;
    unsigned short* Od = Opart + (size_t)slot * MM * DD;
    float* mld = mlpart + (size_t)slot * (BB * HH * TT * 2);

    bf16x8 Qf[NQ][2];
    #pragma unroll
    for (int jb = 0; jb < NQ; ++jb) {
        const unsigned short* qp = q + (size_t)(b * TT + q0w + (jb << 4) + c) * DD + h * DH + (g4 << 3);
        Qf[jb][0] = *(const bf16x8*)qp;
        Qf[jb][1] = *(const bf16x8*)(qp + 32);
    }
    const char* kbase = (const char*)(k + (size_t)b * TT * DD + h * DH);
    const char* vtb   = (const char*)(vt + (size_t)(b * HH + h) * DH * TT);
    char* Pw = lds + 32768 + w * (NQ * 2048);
    const int pkey = (c & 7) << 4;

    f32x4 O[NQ][4] = {};
    float mval[NQ], lpart[NQ];
    #pragma unroll
    for (int jb = 0; jb < NQ; ++jb) { mval[jb] = -1e30f; lpart[jb] = 0.f; }

    const int ntt = CAUSAL ? ((q0 + 64 * NQ) >> 6) : (TT >> 6);
    const int tBeg = half ? ((ntt + 1) >> 1) : 0;
    const int tEnd = half ? ntt : ((ntt + 1) >> 1);

    auto STAGE = [&](int t, int sel) {
        const int kt = t << 6;
        char* Kb = lds + sel * 8192;
        char* Vb = lds + 16384 + sel * 8192;
        #pragma unroll
        for (int c8 = 0; c8 < 2; ++c8) {
            const int qc = (c8 << 2) + w;            // chunk 0..7 (1KB each)
            const int o = (qc << 10) + (lane << 4);
            const int row = o >> 7;                  // 0..63
            const int colb = (o & 127) ^ ((row & 7) << 4);
            gload16(kbase + (size_t)(kt + row) * (DD * 2) + colb, Kb + (qc << 10));
            gload16(vtb + (size_t)row * (TT * 2) + kt * 2 + colb, Vb + (qc << 10));
        }
    };

    if (tBeg < tEnd) {
        STAGE(tBeg, 0);
        asm volatile("s_waitcnt vmcnt(0)" ::: "memory");
        __syncthreads();

        for (int t = tBeg; t < tEnd; ++t) {
            const int cur = (t - tBeg) & 1;
            if (t + 1 < tEnd) STAGE(t + 1, cur ^ 1);
            const int kt = t << 6;

            if (!CAUSAL || kt < kendw) {
                const char* Kb = lds + cur * 8192;
                const char* Vb = lds + 16384 + cur * 8192;

                f32x4 s[NQ][4] = {};
                #pragma unroll
                for (int kk = 0; kk < 2; ++kk) {
                    bf16x8 av[4];
                    #pragma unroll
                    for (int i = 0; i < 4; ++i) {
                        const int r = (i << 4) + c;
                        av[i] = *(const bf16x8*)(Kb + (r << 7) + (((kk << 6) + (g4 << 4)) ^ ((r & 7) << 4)));
                    }
                    #pragma unroll
                    for (int i = 0; i < 4; ++i)
                        #pragma unroll
                        for (int jb = 0; jb < NQ; ++jb)
                            s[jb][i] = __builtin_amdgcn_mfma_f32_16x16x32_bf16(av[i], Qf[jb][kk], s[jb][i], 0, 0, 0);
                }

                #pragma unroll
                for (int jb = 0; jb < NQ; ++jb) {
                    const int qbase = q0w + (jb << 4);
                    if (CAUSAL && kt + 63 > qbase) {
                        #pragma unroll
                        for (int i = 0; i < 4; ++i)
                            #pragma unroll
                            for (int r = 0; r < 4; ++r)
                                if (kt + (i << 4) + (g4 << 2) + r > qbase + c) s[jb][i][r] = -1e30f;
                    }
                    float pmax = -1e30f;
                    #pragma unroll
                    for (int i = 0; i < 4; ++i)
                        #pragma unroll
                        for (int r = 0; r < 4; ++r) pmax = fmaxf(pmax, s[jb][i][r]);
                    if (__any(pmax > mval[jb] + 11.f)) {
                        float mx = fmaxf(pmax, __shfl_xor(pmax, 16));
                        mx = fmaxf(mx, __shfl_xor(mx, 32));
                        const float mn = fmaxf(mval[jb], mx);
                        const float scf = exp2f(mval[jb] - mn);
                        lpart[jb] *= scf;
                        #pragma unroll
                        for (int r = 0; r < 4; ++r) {
                            const float fr = __shfl(scf, (g4 << 2) + r);
                            #pragma unroll
                            for (int jj = 0; jj < 4; ++jj) O[jb][jj][r] *= fr;
                        }
                        mval[jb] = mn;
                    }
                    float ps = 0.f;
                    #pragma unroll
                    for (int i = 0; i < 4; ++i)
                        #pragma unroll
                        for (int r = 0; r < 4; ++r) {
                            const float p = exp2f(s[jb][i][r] - mval[jb]);
                            s[jb][i][r] = p;
                            ps += p;
                        }
                    lpart[jb] += ps;
                    #pragma unroll
                    for (int i = 0; i < 4; ++i) {
                        uint2 pk;
                        pk.x = cvtpk(s[jb][i][0], s[jb][i][1]);
                        pk.y = cvtpk(s[jb][i][2], s[jb][i][3]);
                        const int baddr = (((jb << 4) + c) << 7) + (((i << 4) + (g4 << 2)) << 1);
                        *(uint2*)(Pw + (baddr ^ pkey)) = pk;
                    }
                }
                asm volatile("s_waitcnt lgkmcnt(0)" ::: "memory");
                __builtin_amdgcn_sched_barrier(0);

                #pragma unroll
                for (int kk = 0; kk < 2; ++kk) {
                    bf16x8 pa[NQ];
                    #pragma unroll
                    for (int jb = 0; jb < NQ; ++jb)
                        pa[jb] = *(const bf16x8*)(Pw + (((((jb << 4) + c) << 7) + (kk << 6) + (g4 << 4)) ^ pkey));
                    #pragma unroll
                    for (int jj = 0; jj < 4; ++jj) {
                        const int d = (jj << 4) + c;
                        const bf16x8 vb = *(const bf16x8*)(Vb + (d << 7) + (((kk << 6) + (g4 << 4)) ^ ((d & 7) << 4)));
                        #pragma unroll
                        for (int jb = 0; jb < NQ; ++jb)
                            O[jb][jj] = __builtin_amdgcn_mfma_f32_16x16x32_bf16(pa[jb], vb, O[jb][jj], 0, 0, 0);
                    }
                }
            }

            asm volatile("s_waitcnt vmcnt(0)" ::: "memory");
            __syncthreads();
        }
    }

    // ---- epilogue: store unnormalized O + (m, l) partials ----
    #pragma unroll
    for (int jb = 0; jb < NQ; ++jb) {
        float l2 = lpart[jb] + __shfl_xor(lpart[jb], 16);
        const float ltot = l2 + __shfl_xor(l2, 32);
        #pragma unroll
        for (int jj = 0; jj < 4; ++jj)
            #pragma unroll
            for (int r = 0; r < 4; ++r) {
                const int qr = q0w + (jb << 4) + (g4 << 2) + r;
                Od[(size_t)(b * TT + qr) * DD + h * DH + (jj << 4) + c] = f2bf(O[jb][jj][r]);
            }
        if (lane < 16) {
            const size_t mi = (((size_t)b * HH + h) * TT + q0w + (jb << 4) + lane) * 2;
            mld[mi] = mval[jb];      // log2-domain m
            mld[mi + 1] = ltot;
        }
    }
}

// ---------------------------------------------------------------------------
// Merge partial halves. NS streams summed into out (cross: attnA+attnC
// directly). STOREML stores the LAST stream's (M, L) for avg.
// grid: (MM), 256 threads, 2 d per thread.
// ---------------------------------------------------------------------------
template<int NS, bool STOREML>
__global__ __launch_bounds__(256) void merge_kernel(
    const unsigned short* __restrict__ Opart, const float* __restrict__ mlpart,
    unsigned short* __restrict__ out, float* __restrict__ ml_out)
{
    const int row = blockIdx.x;
    const int b = row >> 11, rt = row & 2047;
    const int t = threadIdx.x;
    const int d0 = t << 1, h = d0 >> 6;
    float acc0 = 0.f, acc1 = 0.f;
    float Ms = 0.f, Ls = 0.f;
    #pragma unroll
    for (int s = 0; s < NS; ++s) {
        const size_t mb = ((size_t)(b * HH + h) * TT + rt) * 2;
        const float* mp0 = mlpart + (size_t)(s * 2 + 0) * (BB * HH * TT * 2) + mb;
        const float* mp1 = mlpart + (size_t)(s * 2 + 1) * (BB * HH * TT * 2) + mb;
        const float m0 = mp0[0], l0 = mp0[1], m1 = mp1[0], l1 = mp1[1];
        const float M = fmaxf(m0, m1);
        const float a0 = exp2f(m0 - M), a1 = exp2f(m1 - M);
        const float inv = 1.f / (a0 * l0 + a1 * l1);
        const unsigned short* p0 = Opart + (size_t)(s * 2 + 0) * MM * DD + (size_t)row * DD + d0;
        const unsigned short* p1 = Opart + (size_t)(s * 2 + 1) * MM * DD + (size_t)row * DD + d0;
        acc0 += (a0 * bf2f(p0[0]) + a1 * bf2f(p1[0])) * inv;
        acc1 += (a0 * bf2f(p0[1]) + a1 * bf2f(p1[1])) * inv;
        if (STOREML && s == NS - 1) { Ms = M; Ls = a0 * l0 + a1 * l1; }
    }
    ((unsigned int*)(out + (size_t)row * DD))[t] = cvtpk(acc0, acc1);
    if (STOREML && (d0 & 63) == 0) {
        float* mo = ml_out + ((size_t)(b * HH + h) * TT + rt) * 2;
        mo[0] = Ms; mo[1] = Ls;
    }
}

// ---------------------------------------------------------------------------
// avg via MFMA: avg[b,q,kt] (+)= (1/(H*L)) * sum_h exp2(q.kc - m)/l
// ---------------------------------------------------------------------------
__global__ __launch_bounds__(64) void avg_mfma_kernel(const unsigned short* __restrict__ qm,
                                                      const unsigned short* __restrict__ kcm,
                                                      const float* __restrict__ ml,
                                                      float* __restrict__ avg, int first)
{
    __shared__ __align__(16) unsigned char ldsQ[8192];
    __shared__ __align__(16) unsigned char ldsK[8192];
    __shared__ float sM[8][64];
    __shared__ float sIL[8][64];
    const int lane = threadIdx.x;
    const int kt0 = blockIdx.x << 6, q0 = blockIdx.y << 6, b = blockIdx.z;

    #pragma unroll
    for (int h = 0; h < 8; ++h) {
        const float* mp = ml + (((size_t)(b * HH + h) * TT) + q0 + lane) * 2;
        sM[h][lane] = mp[0];
        sIL[h][lane] = 1.f / mp[1];
    }

    float avac[4][4][4] = {};
    const int akey = (lane & 7) << 4;
    const int frow = lane & 15;
    const int kq = (lane >> 4) << 4;
    const int crow0 = (lane >> 4) << 2;

    for (int h = 0; h < 8; ++h) {
        __syncthreads();
        #pragma unroll
        for (int c = 0; c < 8; ++c) {
            const int o = (c << 10) + (lane << 4);
            const int row = o >> 7;
            const int colb = (o & 127) ^ ((row & 7) << 4);
            gload16((const char*)qm + ((size_t)(b * TT + q0 + row) * DD + h * DH) * 2 + colb,
                    ldsQ + (c << 10));
            gload16((const char*)kcm + ((size_t)(b * TT + kt0 + row) * DD + h * DH) * 2 + colb,
                    ldsK + (c << 10));
        }
        asm volatile("s_waitcnt vmcnt(0)" ::: "memory");
        __syncthreads();
        f32x4 s[4][4] = {};
        #pragma unroll
        for (int kk = 0; kk < 2; ++kk) {
            bf16x8 qv[4], kv[4];
            #pragma unroll
            for (int i = 0; i < 4; ++i) {
                qv[i] = *(const bf16x8*)(ldsQ + (((i << 4) + frow) << 7) + (((kk << 6) + kq) ^ akey));
                kv[i] = *(const bf16x8*)(ldsK + (((i << 4) + frow) << 7) + (((kk << 6) + kq) ^ akey));
            }
            #pragma unroll
            for (int i = 0; i < 4; ++i)
                #pragma unroll
                for (int j = 0; j < 4; ++j)
                    s[i][j] = __builtin_amdgcn_mfma_f32_16x16x32_bf16(qv[i], kv[j], s[i][j], 0, 0, 0);
        }
        #pragma unroll
        for (int i = 0; i < 4; ++i)
            #pragma unroll
            for (int j = 0; j < 4; ++j)
                #pragma unroll
                for (int r = 0; r < 4; ++r) {
                    const int qr = (i << 4) + crow0 + r;
                    avac[i][j][r] += exp2f(s[i][j][r] - sM[h][qr]) * sIL[h][qr];
                }
    }

    float* dst = avg + ((size_t)b * TT + q0) * TT + kt0;
    #pragma unroll
    for (int i = 0; i < 4; ++i)
        #pragma unroll
        for (int j = 0; j < 4; ++j)
            #pragma unroll
            for (int r = 0; r < 4; ++r) {
                const int qr = (i << 4) + crow0 + r;
                const int kc = (j << 4) + (lane & 15);
                const float v = avac[i][j][r] * (1.f / (HH * LL));
                float* p = dst + (size_t)qr * TT + kc;
                *p = first ? v : (*p + v);
            }
}

// ---------------------------------------------------------------------------
extern "C" void kernel_launch(void* const* d_in, const int* in_sizes, int n_in,
                              void* d_out, int out_size, void* d_ws, size_t ws_size,
                              hipStream_t stream)
{
    const float* x_in   = (const float*)d_in[0];
    const float* enc_a  = (const float*)d_in[1];
    const float* enc_c  = (const float*)d_in[2];
    const float* sa_wq0 = (const float*)d_in[3];
    const float* sa_wk0 = (const float*)d_in[4];
    const float* sa_wv0 = (const float*)d_in[5];
    const float* sa_wo0 = (const float*)d_in[6];
    const float* ed_wq0 = (const float*)d_in[7];
    const float* ed_wk0 = (const float*)d_in[8];
    const float* ed_wv0 = (const float*)d_in[9];
    const float* ed_wo0 = (const float*)d_in[10];
    const float* ffn_w10 = (const float*)d_in[11];
    const float* ffn_w20 = (const float*)d_in[12];
    const float* ln1_g0 = (const float*)d_in[13];
    const float* ln1_b0 = (const float*)d_in[14];
    const float* ln2_g0 = (const float*)d_in[15];
    const float* ln2_b0 = (const float*)d_in[16];
    const float* ln3_g0 = (const float*)d_in[17];
    const float* ln3_b0 = (const float*)d_in[18];
    const float* out_g  = (const float*)d_in[19];
    const float* out_b  = (const float*)d_in[20];

    const size_t NTD = (size_t)MM * DD;       // 2,097,152
    const size_t MB = 1u << 20;
    char* W = (char*)d_ws;
    float*          x_buf   = (float*)(W);                   // 8 MB
    unsigned short* h_bf    = (unsigned short*)(W + 8 * MB); // 4 MB
    unsigned short* q_bf    = (unsigned short*)(W + 12 * MB);
    unsigned short* k1_bf   = (unsigned short*)(W + 16 * MB);
    unsigned short* vt1     = (unsigned short*)(W + 20 * MB); // V_a^T per-head
    unsigned short* k2_bf   = (unsigned short*)(W + 24 * MB);
    unsigned short* vt2     = (unsigned short*)(W + 28 * MB); // V_c^T per-head
    unsigned short* attnA   = (unsigned short*)(W + 32 * MB);
    unsigned short* attnS   = (unsigned short*)(W + 36 * MB);
    float*          ml_buf  = (float*)(W + 40 * MB);         // 256 KB
    unsigned short* encA_bf = (unsigned short*)(W + 41 * MB);
    unsigned short* encC_bf = (unsigned short*)(W + 45 * MB);
    unsigned short* wbf     = (unsigned short*)(W + 49 * MB); // 16.8 MB
    unsigned short* Opart   = (unsigned short*)(W + 68 * MB); // 4 slots x 4MB
    float*          mlpart  = (float*)(W + 84 * MB);          // 4 slots x 256KB
    unsigned short* ffn_bf  = q_bf;   // alias (spans q..k2, all dead in FFN)

    unsigned short* w1t = wbf + (size_t)16 * DD * DD;
    unsigned short* w2t = w1t + (size_t)2 * DD * FF;
    auto wd = [&](int l, int which) { return wbf + ((size_t)(l * 8 + which)) * DD * DD; };

    float* x_out   = (float*)d_out;
    float* avg_out = (float*)d_out + NTD;

    hipMemcpyAsync(x_buf, x_in, NTD * sizeof(float), hipMemcpyDeviceToDevice, stream);

    // ---- setup: all weight transposes in ONE dispatch, enc converts in one ----
    {
        CvtTJobs20 J{};
        const float* srcs[8] = {sa_wq0, sa_wk0, sa_wv0, sa_wo0, ed_wq0, ed_wk0, ed_wv0, ed_wo0};
        for (int l = 0; l < LL; ++l)
            for (int t = 0; t < 8; ++t)
                J.j[l * 8 + t] = {srcs[t] + (size_t)l * DD * DD, wd(l, t), DD, DD};
        for (int l = 0; l < LL; ++l) {
            J.j[16 + l] = {ffn_w10 + (size_t)l * DD * FF, w1t + (size_t)l * FF * DD, DD, FF};
            J.j[18 + l] = {ffn_w20 + (size_t)l * FF * DD, w2t + (size_t)l * DD * FF, FF, DD};
        }
        cvtT_kernel<<<dim3(FF / 32, FF / 32, 20), 256, 0, stream>>>(J);
    }
    {
        CvtEJobs2 J{};
        J.j[0] = {enc_a, encA_bf};
        J.j[1] = {enc_c, encC_bf};
        cvt_kernel<<<dim3(NTD / 8 / 256, 1, 2), 256, 0, stream>>>(J, (int)NTD);
    }

    const dim3 flashSelfG(64, HH, BB);       // NQ=1: 32 q-tiles x 2 halves
    const dim3 flashCrossG(32, HH, BB * 2);  // NQ=2: 16 q-tiles x 2 halves
    const dim3 avgG(TT / 64, TT / 64, BB);
    const float qscale = 0.125f * 1.4426950408889634f;  // dh^-0.5 * log2(e)

    for (int i = 0; i < LL; ++i) {
        const size_t fOff = (size_t)i * DD * FF;
        const size_t lOff = (size_t)i * DD;

        // --- self attention ---
        ln_kernel<true><<<MM, 256, 0, stream>>>(x_buf, ln1_g0 + lOff, ln1_b0 + lOff, h_bf);
        {
            GemmJobs6 J{};
            J.j[0] = {h_bf, wd(i, 0), nullptr, nullptr, q_bf, nullptr, qscale, 0};
            J.j[1] = {h_bf, wd(i, 1), nullptr, nullptr, k1_bf, nullptr, 1.f, 0};
            J.j[2] = {h_bf, wd(i, 2), nullptr, nullptr, nullptr, vt1, 1.f, 0};
            gemm_mfma<<<dim3(DD / 128, MM / 128, 3), 256, 0, stream>>>(J, MM, DD, DD);
        }
        flash_mfma<true, false, 1><<<flashSelfG, 256, 0, stream>>>(
            q_bf, k1_bf, vt1, nullptr, nullptr, Opart, mlpart);
        merge_kernel<1, false><<<MM, 256, 0, stream>>>(Opart, mlpart, attnA, nullptr);
        {
            GemmJobs6 J{};
            J.j[0] = {attnA, wd(i, 3), x_buf, x_buf, nullptr, nullptr, 1.f, 0};
            gemm_mfma<<<dim3(DD / 128, MM / 128, 1), 256, 0, stream>>>(J, MM, DD, DD);
        }

        // --- cross attention (enc_a + enc_c, shared weights) ---
        ln_kernel<true><<<MM, 256, 0, stream>>>(x_buf, ln2_g0 + lOff, ln2_b0 + lOff, h_bf);
        {
            GemmJobs6 J{};
            J.j[0] = {h_bf,    wd(i, 4), nullptr, nullptr, q_bf, nullptr, qscale, 0};
            J.j[1] = {encA_bf, wd(i, 5), nullptr, nullptr, k1_bf, nullptr, 1.f, 0};
            J.j[2] = {encA_bf, wd(i, 6), nullptr, nullptr, nullptr, vt1, 1.f, 0};
            J.j[3] = {encC_bf, wd(i, 5), nullptr, nullptr, k2_bf, nullptr, 1.f, 0};
            J.j[4] = {encC_bf, wd(i, 6), nullptr, nullptr, nullptr, vt2, 1.f, 0};
            gemm_mfma<<<dim3(DD / 128, MM / 128, 5), 256, 0, stream>>>(J, MM, DD, DD);
        }
        flash_mfma<false, true, 2><<<flashCrossG, 256, 0, stream>>>(
            q_bf, k1_bf, vt1, k2_bf, vt2, Opart, mlpart);
        merge_kernel<2, true><<<MM, 256, 0, stream>>>(Opart, mlpart, attnS, ml_buf);
        avg_mfma_kernel<<<avgG, 64, 0, stream>>>(q_bf, k2_bf, ml_buf, avg_out, (i == 0) ? 1 : 0);
        {
            GemmJobs6 J{};
            J.j[0] = {attnS, wd(i, 7), x_buf, x_buf, nullptr, nullptr, 1.f, 0};
            gemm_mfma<<<dim3(DD / 128, MM / 128, 1), 256, 0, stream>>>(J, MM, DD, DD);
        }

        // --- FFN ---
        ln_kernel<true><<<MM, 256, 0, stream>>>(x_buf, ln3_g0 + lOff, ln3_b0 + lOff, h_bf);
        {
            GemmJobs6 J{};
            J.j[0] = {h_bf, w1t + fOff, nullptr, nullptr, ffn_bf, nullptr, 1.f, 1};
            gemm_mfma<<<dim3(FF / 128, MM / 128, 1), 256, 0, stream>>>(J, MM, FF, DD);
        }
        {
            GemmJobs6 J{};
            J.j[0] = {ffn_bf, w2t + fOff, x_buf, x_buf, nullptr, nullptr, 1.f, 0};
            gemm_mfma<<<dim3(DD / 128, MM / 128, 1), 256, 0, stream>>>(J, MM, DD, FF);
        }
    }

    ln_kernel<false><<<MM, 256, 0, stream>>>(x_buf, out_g, out_b, x_out);
}